// Round 8
// baseline (49.983 us; speedup 1.0000x reference)
//
#include <hip/hip_runtime.h>

#define NN 1026   // nodes
#define NA 1024   // angles
#define BLK 1024
typedef float v2f __attribute__((ext_vector_type(2)));

__device__ __forceinline__ v2f vbc(float s) { return (v2f){s, s}; }

// minimax atan2, max err ~2e-6 rad; inputs never both zero here
__device__ __forceinline__ float fast_atan2f(float y, float x) {
    float ax = __builtin_fabsf(x), ay = __builtin_fabsf(y);
    float mx = fmaxf(ax, ay), mn = fminf(ax, ay);
    float a  = mn * __builtin_amdgcn_rcpf(mx);
    float s  = a * a;
    float r  = fmaf(s, -0.0117212f,  0.05265332f);
    r = fmaf(s, r, -0.11643287f);
    r = fmaf(s, r,  0.19354346f);
    r = fmaf(s, r, -0.33262347f);
    r = fmaf(s, r,  0.99997726f);
    r *= a;
    if (ay > ax)  r = 1.57079637f - r;
    if (x < 0.0f) r = 3.14159274f - r;
    return copysignf(r, y);
}

__global__ __launch_bounds__(BLK)
void equil_kernel(const float* __restrict__ pos0,
                  const float* __restrict__ tip_pos,
                  const float* __restrict__ thetas_ss,
                  const int*   __restrict__ buckle,
                  const float* __restrict__ kstiff_p,
                  const float* __restrict__ ksoft_p,
                  const float* __restrict__ kstretch_p,
                  float* __restrict__ out)
{
    __shared__ v2f    pos[NN];       // node positions
    __shared__ float4 PB4[NA + 1];   // slot j: {P_j.x,P_j.y,B_j.x,B_j.y}; slot 1024: {S_1024, *}

    const int b = blockIdx.x;
    const int t = threadIdx.x;
    const float k_str  = kstretch_p[0];
    const float k_sd   = kstiff_p[0] - ksoft_p[0];
    const float k4soft = 4.0f * ksoft_p[0];

    // ---- init: thread t computes angle t, owns node t+2 (free for t<=1022) ----
    const v2f* p0g = (const v2f*)(pos0 + (size_t)b * 2052);
    v2f myp;
    if (t < 1023) myp = p0g[t + 2];
    else          myp = (v2f){tip_pos[2*b], tip_pos[2*b+1]};
    pos[t + 2] = myp;
    if (t < 2) pos[t] = p0g[t];      // fixed nodes 0,1

    const float TH = thetas_ss[t];
    const int4 bk  = ((const int4*)buckle)[t];
    const float npl = (float)(bk.x + bk.y + bk.z + bk.w);   // #(pm==+1)
    v2f vel = vbc(0.f);
    __syncthreads();

#pragma unroll 2
    for (int s = 0; s < 64; ++s) {
        // ---- phase AB: angle t from pos[t], pos[t+1], own myp ----
        v2f pa = pos[t], pb = pos[t + 1];
        v2f v1 = pb - pa;
        v2f v2 = myp - pb;
        float l2a = fmaf(v1.x, v1.x, v1.y * v1.y);
        float l2b = fmaf(v2.x, v2.x, v2.y * v2.y);
        float cr  = v1.x * v2.y - v1.y * v2.x;
        float dt_ = fmaf(v1.x, v2.x, v1.y * v2.y);
        float theta = fast_atan2f(cr, dt_);
        float cnt = (theta <  TH ? npl        : 0.f)
                  + (theta > -TH ? 4.f - npl  : 0.f);
        float K = fmaf(cnt, k_sd, k4soft);
        float m = K * (theta - TH);
        float ila = __builtin_amdgcn_rsqf(l2a);
        float ilb = __builtin_amdgcn_rsqf(l2b);
        float m1 = m * ila * ila;                 // m / l2a
        float m2 = m * ilb * ilb;                 // m / l2b
        v2f rot1 = (v2f){ v1.y, -v1.x};
        v2f rot2 = (v2f){ v2.y, -v2.x};
        v2f Bv = vbc(-m2) * rot2;                 // b_t
        float sca = k_str * (1.0f - ila);         // k*(len_a-1)/len_a
        v2f P  = vbc(sca) * v1 + vbc(m1) * rot1;  // S_t + a_t
        PB4[t] = make_float4(P.x, P.y, Bv.x, Bv.y);
        if (t == NA - 1) {   // slot 1024: P = S_1024 (stretch-only edge)
            float scb = k_str * (1.0f - ilb);
            PB4[NA] = make_float4(scb * v2.x, scb * v2.y, 0.f, 0.f);
        }
        __syncthreads();

        // ---- phase C: f(node t+2) = P[t+2] - (P[t+1]-B[t+1]) - B[t] ----
        if (t < 1023) {
            float4 n1 = PB4[t + 1];
            v2f P2 = ((const v2f*)PB4)[2 * (t + 2)];   // P part of slot t+2
            v2f Qm = (v2f){n1.x - n1.z, n1.y - n1.w};  // Q_{t+1} = P - B (bit-identical)
            v2f f  = (P2 - Qm) - Bv;
            vel = vel + vbc(0.001f) * (f - vbc(2.0f) * vel);
            myp = myp + vbc(0.001f) * vel;
            pos[t + 2] = myp;
        }
        __syncthreads();
    }

    // ---- epilogue ----
    v2f* o = (v2f*)(out + (size_t)b * 2052);
    o[t + 2] = myp;            // t=1023 writes node 1025 = tip
    if (t < 2) o[t] = pos[t];
}

extern "C" void kernel_launch(void* const* d_in, const int* in_sizes, int n_in,
                              void* d_out, int out_size, void* d_ws, size_t ws_size,
                              hipStream_t stream) {
    const float* pos0   = (const float*)d_in[0];
    const float* tip    = (const float*)d_in[1];
    const float* thetas = (const float*)d_in[2];
    const int*   buckle = (const int*)  d_in[3];
    const float* ks     = (const float*)d_in[4];
    const float* ko     = (const float*)d_in[5];
    const float* kr     = (const float*)d_in[6];
    float* out = (float*)d_out;
    hipLaunchKernelGGL(equil_kernel, dim3(256), dim3(BLK), 0, stream,
                       pos0, tip, thetas, buckle, ks, ko, kr, out);
}